// Round 10
// baseline (42.873 us; speedup 1.0000x reference)
//
#include <hip/hip_runtime.h>
#include <math.h>

// Gaussian KDE, n=12000. 3 dispatches:
//   1) sel_k 1x1024: stats+min/max; EXACT Q25/Q75 via value-linear 2048-bin
//      histogram + candidate rank-select; computes h; writes pre-scaled ejwj[].
//   2) kde_k grid(24,32)x256: II=8 (i-tile 512), j-window 384.
//      partial[y*nmax+i] = sum_{j in win} w'_j * exp2(-(e_i-e_j)^2)
//   3) fin_k 48x256: out[i] = log(sum_{y<32} partial[y][i] + 1e-10)
// Fixed accumulation orders; int atomics order-independent -> bit-deterministic.

#define BLK 256
#define YWK 32
#define ITILE 512
#define MAXWIN 384
#define MAXN 12032
#define NB 2048
#define CAND 512

#if defined(__has_builtin)
#if __has_builtin(__builtin_amdgcn_exp2f)
#define EXP2(x) __builtin_amdgcn_exp2f(x)
#endif
#endif
#ifndef EXP2
#define EXP2(x) exp2f(x)
#endif

__global__ __launch_bounds__(1024) void sel_k(const float* __restrict__ d,
                                              const float* __restrict__ w,
                                              float2* __restrict__ ejwj,
                                              int n, int nmax) {
    __shared__ float sdata[MAXN];    // 48.1 KB
    __shared__ int hist[NB];         // 8 KB
    __shared__ int cum[NB];          // 8 KB
    __shared__ float cand[4][CAND];  // 8 KB
    __shared__ int ccnt[4];
    __shared__ int tb[4], tprev[4];
    __shared__ float4 sstat[16];
    __shared__ float2 smm[16];
    __shared__ int wtot[16];
    __shared__ float sq[4];
    __shared__ float sparams[2];
    __shared__ float slh[2];

    const int t = threadIdx.x, lane = t & 63, wid = t >> 6;

    for (int b = t; b < NB; b += 1024) hist[b] = 0;
    if (t < 4) ccnt[t] = 0;

    // ---- pass 1: stage d in LDS; stats + min/max partials ----
    float s1 = 0.f, s2 = 0.f, sd = 0.f, sd2 = 0.f;
    float mn = __int_as_float(0x7f800000), mx = __int_as_float(0xff800000);
    for (int i = t; i < n; i += 1024) {
        float dv = d[i], wv = w[i];
        sdata[i] = dv;
        s1 += wv; s2 += wv * wv; sd += dv; sd2 += dv * dv;
        mn = fminf(mn, dv); mx = fmaxf(mx, dv);
    }
    for (int off = 32; off > 0; off >>= 1) {
        s1 += __shfl_down(s1, off); s2 += __shfl_down(s2, off);
        sd += __shfl_down(sd, off); sd2 += __shfl_down(sd2, off);
        mn = fminf(mn, __shfl_down(mn, off));
        mx = fmaxf(mx, __shfl_down(mx, off));
    }
    if (lane == 0) { sstat[wid] = make_float4(s1, s2, sd, sd2); smm[wid] = make_float2(mn, mx); }
    __syncthreads();
    if (t == 0) {
        float lo = smm[0].x, hi = smm[0].y;
        for (int q = 1; q < 16; ++q) { lo = fminf(lo, smm[q].x); hi = fmaxf(hi, smm[q].y); }
        slh[0] = lo; slh[1] = hi;
    }
    __syncthreads();
    const float lo = slh[0];
    const float range = slh[1] - lo;
    const float scale = (range > 0.f) ? (float)NB / range : 0.f;

    // ---- pass 2: value-linear histogram (monotone binning -> exact ranks) ----
    for (int i = t; i < n; i += 1024) {
        int b = (int)((sdata[i] - lo) * scale);
        atomicAdd(&hist[b < NB ? b : NB - 1], 1);
    }
    __syncthreads();

    // ---- inclusive scan hist -> cum ----
    {
        const int b0 = t * 2;
        int a0 = hist[b0], a1 = hist[b0 + 1];
        int seg = a0 + a1, v = seg;
        for (int off = 1; off < 64; off <<= 1) {
            int u = __shfl_up(v, off);
            if (lane >= off) v += u;
        }
        if (lane == 63) wtot[wid] = v;
        __syncthreads();
        if (t == 0) {
            int acc = 0;
            for (int q = 0; q < 16; ++q) { int tmp = wtot[q]; wtot[q] = acc; acc += tmp; }
        }
        __syncthreads();
        int excl = wtot[wid] + (v - seg);
        cum[b0] = excl + a0;
        cum[b0 + 1] = excl + a0 + a1;
        __syncthreads();
    }

    // ---- locate target bins ----
    const double p25 = 0.25 * (double)(n - 1);
    const double p75 = 0.75 * (double)(n - 1);
    const int l25 = (int)p25, l75 = (int)p75;
    const int u25 = (l25 + 1 < n) ? l25 + 1 : l25;
    const int u75 = (l75 + 1 < n) ? l75 + 1 : l75;
    const int targets[4] = {l25, u25, l75, u75};
    for (int b = t; b < NB; b += 1024) {
        int incl = cum[b], prev = b ? cum[b - 1] : 0;
        #pragma unroll
        for (int r = 0; r < 4; ++r)
            if (prev <= targets[r] && targets[r] < incl) { tb[r] = b; tprev[r] = prev; }
    }
    __syncthreads();

    // ---- pass 3: collect candidates of the (<=4) target bins ----
    const int tb0 = tb[0], tb1 = tb[1], tb2 = tb[2], tb3 = tb[3];
    for (int i = t; i < n; i += 1024) {
        float dv = sdata[i];
        int b = (int)((dv - lo) * scale);
        b = b < NB ? b : NB - 1;
        if (b == tb0) { int p = atomicAdd(&ccnt[0], 1); if (p < CAND) cand[0][p] = dv; }
        if (b == tb1) { int p = atomicAdd(&ccnt[1], 1); if (p < CAND) cand[1][p] = dv; }
        if (b == tb2) { int p = atomicAdd(&ccnt[2], 1); if (p < CAND) cand[2][p] = dv; }
        if (b == tb3) { int p = atomicAdd(&ccnt[3], 1); if (p < CAND) cand[3][p] = dv; }
    }
    __syncthreads();

    // ---- exact rank-select within candidate arrays (wave r per target) ----
    if (wid < 4) {
        const int r = wid;
        const int kk = targets[r] - tprev[r];
        const int m = ccnt[r] < CAND ? ccnt[r] : CAND;
        for (int ci = lane; ci < m; ci += 64) {
            float v = cand[r][ci];
            int rk = 0;
            for (int j = 0; j < m; ++j) {
                float u = cand[r][j];
                rk += (u < v) || (u == v && j < ci);   // index tiebreak: distinct ranks
            }
            if (rk == kk) sq[r] = v;                    // kk-th smallest: perm-invariant
        }
    }
    __syncthreads();

    // ---- h + scales ----
    if (t == 0) {
        double S1 = 0, S2 = 0, Sd = 0, Sd2 = 0;
        for (int q = 0; q < 16; ++q) {
            float4 v = sstat[q];
            S1 += v.x; S2 += v.y; Sd += v.z; Sd2 += v.w;
        }
        double neff = S1 * S1 / S2;
        double var  = (Sd2 - Sd * Sd / (double)n) / ((double)n - 1.0);
        double sdev = sqrt(var);
        double f25 = p25 - (double)l25, f75 = p75 - (double)l75;
        double q25 = (double)sq[0] + f25 * ((double)sq[1] - (double)sq[0]);
        double q75 = (double)sq[2] + f75 * ((double)sq[3] - (double)sq[2]);
        double sig = fmin(sdev, (q75 - q25) / 1.34);
        double h = 0.9 * sig * pow(neff, -0.2);
        sparams[0] = (float)(sqrt(0.5 * 1.4426950408889634) / h);          // r
        sparams[1] = (float)(1.0 / (h * sqrt(6.283185307179586) * S1));    // wsc
    }
    __syncthreads();
    const float rr = sparams[0], wsc = sparams[1];
    for (int j = t; j < nmax; j += 1024)
        ejwj[j] = (j < n) ? make_float2(sdata[j] * rr, w[j] * wsc) : make_float2(0.f, 0.f);
}

__global__ __launch_bounds__(BLK) void kde_k(const float2* __restrict__ ejwj,
                                             float* __restrict__ partial,
                                             int n, int nmax, int WIN) {
    __shared__ float2 sj[MAXWIN];    // 3 KB
    __shared__ float sredf[2048];    // 8 KB
    const int t = threadIdx.x, ib = blockIdx.x, y = blockIdx.y;
    const int lane = t & 63, wv = t >> 6;
    const int j0 = y * WIN;

    for (int idx = t; idx < (WIN >> 1); idx += BLK)
        ((float4*)sj)[idx] = ((const float4*)(ejwj + j0))[idx];
    const int i0 = ib * ITILE + lane;
    float ei[8];
    #pragma unroll
    for (int k = 0; k < 8; ++k) ei[k] = ejwj[i0 + 64 * k].x;
    __syncthreads();

    float a[8];
    #pragma unroll
    for (int k = 0; k < 8; ++k) a[k] = 0.f;
    {
        const float4* pj = (const float4*)(sj + wv * (WIN >> 2));  // 96 float2/wave
        const int nq = WIN >> 3;  // 48 float4 = 96 j's per wave slice
        for (int jj = 0; jj < nq; ++jj) {
            float4 q = pj[jj];  // (e_a, w_a, e_b, w_b)
            #pragma unroll
            for (int k = 0; k < 8; ++k) {
                float u = ei[k] - q.x;
                float v = ei[k] - q.z;
                a[k] = fmaf(q.y, EXP2(-(u * u)), a[k]);
                a[k] = fmaf(q.w, EXP2(-(v * v)), a[k]);
            }
        }
    }
    __syncthreads();
    #pragma unroll
    for (int k = 0; k < 8; ++k) sredf[wv * 512 + k * 64 + lane] = a[k];
    __syncthreads();
    #pragma unroll
    for (int o = 0; o < 2; ++o) {
        int oo = t + o * 256;
        partial[y * nmax + ib * ITILE + oo] =
            sredf[oo] + sredf[512 + oo] + sredf[1024 + oo] + sredf[1536 + oo];
    }
}

__global__ __launch_bounds__(BLK) void fin_k(const float* __restrict__ partial,
                                             float* __restrict__ out, int n, int nmax) {
    int i = blockIdx.x * BLK + threadIdx.x;
    if (i < n) {
        float p = 0.f;
        #pragma unroll
        for (int y = 0; y < YWK; ++y) p += partial[y * nmax + i];
        out[i] = logf(p + 1e-10f);
    }
}

extern "C" void kernel_launch(void* const* d_in, const int* in_sizes, int n_in,
                              void* d_out, int out_size, void* d_ws, size_t ws_size,
                              hipStream_t stream) {
    const float* d = (const float*)d_in[0];
    const float* w = (const float*)d_in[1];
    float* out = (float*)d_out;
    const int n = in_sizes[0];

    const int nmax = ((n + ITILE - 1) / ITILE) * ITILE;   // 12288 (mult of 512 & 32)
    const int IB = nmax / ITILE;                          // 24
    const int WIN = nmax / YWK;                           // 384

    // ws layout (float units): ejwj float2[nmax] | partial float[YWK*nmax]
    float*  wsf     = (float*)d_ws;
    float2* ejwj    = (float2*)wsf;
    float*  partial = wsf + 2 * nmax;

    sel_k<<<1, 1024, 0, stream>>>(d, w, ejwj, n, nmax);
    dim3 grid(IB, YWK);
    kde_k<<<grid, BLK, 0, stream>>>(ejwj, partial, n, nmax, WIN);
    fin_k<<<nmax / BLK, BLK, 0, stream>>>(partial, out, n, nmax);
}